// Round 26
// baseline (293.223 us; speedup 1.0000x reference)
//
#include <hip/hip_runtime.h>
#include <hip/hip_bf16.h>

#define BB 16
#define NN 512
#define DD 64
#define BN_ROWS (BB * NN)   // 8192

typedef unsigned short ushort;
typedef unsigned int uint;
typedef short bf16x8 __attribute__((ext_vector_type(8)));   // 8 bf16 = 4 VGPRs
typedef float f32x4  __attribute__((ext_vector_type(4)));   // MFMA acc

// ws layout: stats[128] | wpf fp32 frag-ordered [4096] | xbf bf16 frag-ordered [524288]
// R26 = R25 + (1) Pade(3,2) tanh (1 trans instead of 2), (2) all 8 B-frag
// loads hoisted ahead of the fully-unrolled fused loop.

__device__ __forceinline__ uint pkbf2(float lo, float hi) {
    union { float f; uint u; } a, b; a.f = lo; b.f = hi;
    return __builtin_amdgcn_perm(b.u + 0x8000u, a.u + 0x8000u, 0x07060302u);
}
__device__ __forceinline__ float bflo(uint u) {
    union { uint i; float f; } c; c.i = u << 16; return c.f;
}
__device__ __forceinline__ float bfhi(uint u) {
    union { uint i; float f; } c; c.i = u & 0xffff0000u; return c.f;
}

// Pade(3,2) on clamped [-3,3]: max err ~5e-3 (at saturation), 6 VALU + 1 trans.
__device__ __forceinline__ float fast_tanh(float x) {
    x = fminf(3.0f, fmaxf(-3.0f, x));
    const float t = x * x;
    return x * (27.0f + t) * __builtin_amdgcn_rcpf(fmaf(9.0f, t, 27.0f));
}

// One-time: x -> bf16 B-frag order; Wp -> fp32 A-frag order; zero stats.
__global__ __launch_bounds__(256) void prep_kernel(
    const float* __restrict__ x, const float* __restrict__ Wp,
    float* __restrict__ wpf, ushort* __restrict__ xbf, float* __restrict__ stats)
{
    const int tid = blockIdx.x * 256 + threadIdx.x;     // grid 256 -> 0..65535
    const int b = tid >> 12, rem = tid & 4095;
    const int jt = rem >> 7, ks = (rem >> 6) & 1, lane = rem & 63;
    const int qd = lane >> 4, ln = lane & 15;
    const float* __restrict__ src =
        x + ((size_t)(b * NN + jt * 16 + ln)) * DD + ks * 32 + qd * 8;
    const float4 v0 = *(const float4*)src;
    const float4 v1 = *(const float4*)(src + 4);
    uint4 o;
    o.x = pkbf2(v0.x, v0.y); o.y = pkbf2(v0.z, v0.w);
    o.z = pkbf2(v1.x, v1.y); o.w = pkbf2(v1.z, v1.w);
    ((uint4*)xbf)[tid] = o;                              // coalesced
    if (tid < DD * DD) {
        const int oo = tid >> 6, d = tid & 63;
        const int mt = oo >> 4, l2 = oo & 15;
        const int k2 = d >> 5, q2 = (d >> 3) & 3, e = d & 7;
        wpf[(((mt * 2 + k2) * 64) + (q2 * 16 + l2)) * 8 + e] = Wp[tid];
    }
    if (tid < 128) stats[tid] = 0.0f;
}

// One block (512 thr, 8 waves) per (b,i); wave wv owns j-tiles wv*4..wv*4+3.
// XCD swizzle: b = (blk&7)*2 + ((blk>>3)&1), i = blk>>4.
__global__ __launch_bounds__(512, 3) void attn_kernel(
    const float* __restrict__ x,  const float* __restrict__ wpf,
    const ushort* __restrict__ xbf,
    const float* __restrict__ bp, const float* __restrict__ aw,
    const float* __restrict__ W1, const float* __restrict__ b1,
    const float* __restrict__ W2, const float* __restrict__ b2,
    float* __restrict__ out, float* __restrict__ stats)
{
    __shared__ float part[8][DD];                   // 2 KB (reused twice)
    __shared__ __align__(16) float s_xi[DD], s_agg[DD], s_bp[DD], s_aw[DD];
    __shared__ float s_esum[8];

    const int t = threadIdx.x;                      // 0..511
    const int wv = t >> 6, lane = t & 63;
    const int blk = blockIdx.x;                     // 0..8191
    const int b = (blk & 7) * 2 + ((blk >> 3) & 1); // XCD-local b
    const int i = blk >> 4;                         // 0..511
    const int row = b * NN + i;
    const int qd = lane >> 4, ln = lane & 15;
    const ushort* __restrict__ xb16 = xbf + (size_t)b * (NN * DD);

    if (t < DD) {
        s_bp[t] = bp[t];
        s_aw[t] = aw[t];
        s_xi[t] = x[(size_t)row * DD + t];
    }
    __syncthreads();

    // hoist ALL 8 tile loads (4 tiles x 2 halves) before any compute
    union { bf16x8 v; uint4 u; } tl[4][2];
    #pragma unroll
    for (int tt = 0; tt < 4; ++tt) {
        const int tile = wv * 4 + tt;
        tl[tt][0].v = *(const bf16x8*)(xb16 + ((tile * 2 + 0) * 64 + lane) * 8);
        tl[tt][1].v = *(const bf16x8*)(xb16 + ((tile * 2 + 1) * 64 + lane) * 8);
    }

    float xiv[2][8];
    #pragma unroll
    for (int ks = 0; ks < 2; ++ks) {
        const float4 a = *(const float4*)(s_xi + ks * 32 + qd * 8);
        const float4 c = *(const float4*)(s_xi + ks * 32 + qd * 8 + 4);
        xiv[ks][0]=a.x; xiv[ks][1]=a.y; xiv[ks][2]=a.z; xiv[ks][3]=a.w;
        xiv[ks][4]=c.x; xiv[ks][5]=c.y; xiv[ks][6]=c.z; xiv[ks][7]=c.w;
    }

    // A-frags: Wp⊙xi in bf16, g = mt*2+ks
    bf16x8 afrag[8];
    #pragma unroll
    for (int g = 0; g < 8; ++g) {
        const int ks = g & 1;
        const float4 wa = *(const float4*)(wpf + (g * 64 + lane) * 8);
        const float4 wb = *(const float4*)(wpf + (g * 64 + lane) * 8 + 4);
        union { bf16x8 v; uint u[4]; } p;
        p.u[0] = pkbf2(wa.x * xiv[ks][0], wa.y * xiv[ks][1]);
        p.u[1] = pkbf2(wa.z * xiv[ks][2], wa.w * xiv[ks][3]);
        p.u[2] = pkbf2(wb.x * xiv[ks][4], wb.y * xiv[ks][5]);
        p.u[3] = pkbf2(wb.z * xiv[ks][6], wb.w * xiv[ks][7]);
        afrag[g] = p.v;
    }

    float bpv[16], awv[16];
    #pragma unroll
    for (int mt = 0; mt < 4; ++mt)
        #pragma unroll
        for (int r = 0; r < 4; ++r) {
            bpv[mt * 4 + r] = s_bp[mt * 16 + qd * 4 + r];
            awv[mt * 4 + r] = s_aw[mt * 16 + qd * 4 + r];
        }

    // ---- FUSED score + aggregate over the 4 preloaded tiles ----
    float vacc[16];
    #pragma unroll
    for (int k = 0; k < 16; ++k) vacc[k] = 0.0f;
    float esum = 0.0f;

    #pragma unroll
    for (int tt = 0; tt < 4; ++tt) {
        float s0 = 0.0f, s1 = 0.0f, s2 = 0.0f, s3 = 0.0f;
        #pragma unroll
        for (int mt = 0; mt < 4; ++mt) {
            f32x4 acc = { bpv[mt*4+0], bpv[mt*4+1], bpv[mt*4+2], bpv[mt*4+3] };
            acc = __builtin_amdgcn_mfma_f32_16x16x32_bf16(afrag[mt*2+0], tl[tt][0].v, acc, 0, 0, 0);
            acc = __builtin_amdgcn_mfma_f32_16x16x32_bf16(afrag[mt*2+1], tl[tt][1].v, acc, 0, 0, 0);
            s0 = fmaf(awv[mt*4+0], fast_tanh(acc[0]), s0);
            s1 = fmaf(awv[mt*4+1], fast_tanh(acc[1]), s1);
            s2 = fmaf(awv[mt*4+2], fast_tanh(acc[2]), s2);
            s3 = fmaf(awv[mt*4+3], fast_tanh(acc[3]), s3);
        }
        float sj = (s0 + s1) + (s2 + s3);
        sj += __shfl_xor(sj, 16);
        sj += __shfl_xor(sj, 32);        // all quads: s for j = tile*16 + ln

        const float e = __builtin_amdgcn_exp2f(sj * 1.4426950408889634f);
        esum += e;
        vacc[0]  = fmaf(e, bflo(tl[tt][0].u.x), vacc[0]);
        vacc[1]  = fmaf(e, bfhi(tl[tt][0].u.x), vacc[1]);
        vacc[2]  = fmaf(e, bflo(tl[tt][0].u.y), vacc[2]);
        vacc[3]  = fmaf(e, bfhi(tl[tt][0].u.y), vacc[3]);
        vacc[4]  = fmaf(e, bflo(tl[tt][0].u.z), vacc[4]);
        vacc[5]  = fmaf(e, bfhi(tl[tt][0].u.z), vacc[5]);
        vacc[6]  = fmaf(e, bflo(tl[tt][0].u.w), vacc[6]);
        vacc[7]  = fmaf(e, bfhi(tl[tt][0].u.w), vacc[7]);
        vacc[8]  = fmaf(e, bflo(tl[tt][1].u.x), vacc[8]);
        vacc[9]  = fmaf(e, bfhi(tl[tt][1].u.x), vacc[9]);
        vacc[10] = fmaf(e, bflo(tl[tt][1].u.y), vacc[10]);
        vacc[11] = fmaf(e, bfhi(tl[tt][1].u.y), vacc[11]);
        vacc[12] = fmaf(e, bflo(tl[tt][1].u.z), vacc[12]);
        vacc[13] = fmaf(e, bfhi(tl[tt][1].u.z), vacc[13]);
        vacc[14] = fmaf(e, bflo(tl[tt][1].u.w), vacc[14]);
        vacc[15] = fmaf(e, bfhi(tl[tt][1].u.w), vacc[15]);
    }

    // reduce over ln within wave
    #pragma unroll
    for (int off = 1; off < 16; off <<= 1) {
        esum += __shfl_xor(esum, off);
        #pragma unroll
        for (int k = 0; k < 16; ++k)
            vacc[k] += __shfl_xor(vacc[k], off);
    }
    if (lane == 0) s_esum[wv] = esum;
    if (ln == 0) {
        #pragma unroll
        for (int k = 0; k < 16; ++k)
            part[wv][(k >> 3) * 32 + qd * 8 + (k & 7)] = vacc[k];
    }
    __syncthreads();

    // block combine: agg[d] = (Σ_wv part[wv][d]) / (Σ_wv esum[wv])
    if (t < DD) {
        const float tot = ((s_esum[0] + s_esum[1]) + (s_esum[2] + s_esum[3]))
                        + ((s_esum[4] + s_esum[5]) + (s_esum[6] + s_esum[7]));
        const float inv = 1.0f / tot;
        const float a = ((part[0][t] + part[1][t]) + (part[2][t] + part[3][t]))
                      + ((part[4][t] + part[5][t]) + (part[6][t] + part[7][t]));
        s_agg[t] = a * inv;
    }
    __syncthreads();

    // projection: 512 threads; thread (o, q) sums 8 d's
    {
        const int o = t & 63, q = t >> 6;
        const float4 w1a = *(const float4*)(W1 + o * DD + q * 8);
        const float4 w1b = *(const float4*)(W1 + o * DD + q * 8 + 4);
        const float4 w2a = *(const float4*)(W2 + o * DD + q * 8);
        const float4 w2b = *(const float4*)(W2 + o * DD + q * 8 + 4);
        const float4 aga = *(const float4*)(s_agg + q * 8);
        const float4 agb = *(const float4*)(s_agg + q * 8 + 4);
        const float4 xia = *(const float4*)(s_xi + q * 8);
        const float4 xib = *(const float4*)(s_xi + q * 8 + 4);
        float v = 0.0f;
        v = fmaf(w1a.x, aga.x, fmaf(w2a.x, xia.x, v));
        v = fmaf(w1a.y, aga.y, fmaf(w2a.y, xia.y, v));
        v = fmaf(w1a.z, aga.z, fmaf(w2a.z, xia.z, v));
        v = fmaf(w1a.w, aga.w, fmaf(w2a.w, xia.w, v));
        v = fmaf(w1b.x, agb.x, fmaf(w2b.x, xib.x, v));
        v = fmaf(w1b.y, agb.y, fmaf(w2b.y, xib.y, v));
        v = fmaf(w1b.z, agb.z, fmaf(w2b.z, xib.z, v));
        v = fmaf(w1b.w, agb.w, fmaf(w2b.w, xib.w, v));
        part[q][o] = v;
    }
    __syncthreads();
    if (t < DD) {
        const int o = t;
        const float v = b1[o] + b2[o]
            + ((part[0][o] + part[1][o]) + (part[2][o] + part[3][o]))
            + ((part[4][o] + part[5][o]) + (part[6][o] + part[7][o]));
        out[(size_t)row * DD + o] = v;     // pre-BN x_out into d_out
        atomicAdd(&stats[o], v);
        atomicAdd(&stats[64 + o], v * v);
    }
}

// BN (batch stats, biased var) + selu, IN PLACE on out; float4 I/O.
__global__ __launch_bounds__(256) void final_kernel(
    const float* __restrict__ stats,
    const float* __restrict__ gamma, const float* __restrict__ beta,
    float* __restrict__ out)
{
    __shared__ float smu[DD], sga[DD], sbe[DD];
    if (threadIdx.x < DD) {
        const int o = threadIdx.x;
        const float mean = stats[o] * (1.0f / BN_ROWS);
        const float var  = stats[64 + o] * (1.0f / BN_ROWS) - mean * mean;
        smu[o] = mean;
        sga[o] = gamma[o] / sqrtf(var + 1e-5f);
        sbe[o] = beta[o];
    }
    __syncthreads();
    const int i4 = blockIdx.x * 256 + threadIdx.x;   // grid 512 -> exactly 131072
    const int o0 = (i4 & 15) * 4;
    const float4 v = ((const float4*)out)[i4];
    float r[4] = { v.x, v.y, v.z, v.w };
    #pragma unroll
    for (int c = 0; c < 4; ++c) {
        const float nrm = (r[c] - smu[o0 + c]) * sga[o0 + c] + sbe[o0 + c];
        r[c] = nrm > 0.0f
            ? 1.0507009873554805f * nrm
            : 1.7580993408473766f * expm1f(nrm);
    }
    ((float4*)out)[i4] = make_float4(r[0], r[1], r[2], r[3]);
}

extern "C" void kernel_launch(void* const* d_in, const int* in_sizes, int n_in,
                              void* d_out, int out_size, void* d_ws, size_t ws_size,
                              hipStream_t stream)
{
    const float* x  = (const float*)d_in[0];
    const float* Wp = (const float*)d_in[1];  // W_att_proj
    const float* bp = (const float*)d_in[2];  // b_att_proj
    const float* aw = (const float*)d_in[3];  // att_weight
    const float* W1 = (const float*)d_in[4];  // W_with
    const float* b1 = (const float*)d_in[5];  // b_with
    const float* W2 = (const float*)d_in[6];  // W_without
    const float* b2 = (const float*)d_in[7];  // b_without
    const float* ga = (const float*)d_in[8];  // gamma
    const float* be = (const float*)d_in[9];  // beta

    float*  stats = (float*)d_ws;                       // 128 floats
    float*  wpf   = stats + 128;                        // 4096 fp32 (A-frag order)
    ushort* xbf   = (ushort*)(wpf + DD * DD);           // 524288 bf16 (B-frag order)
    float*  out   = (float*)d_out;                      // fp32 output

    prep_kernel<<<256, 256, 0, stream>>>(x, Wp, wpf, xbf, stats);
    attn_kernel<<<BN_ROWS, 512, 0, stream>>>(x, wpf, xbf, bp, aw, W1, b1, W2, b2, out, stats);
    final_kernel<<<512, 256, 0, stream>>>(stats, ga, be, out);
}

// Round 27
// 279.605 us; speedup vs baseline: 1.0487x; 1.0487x over previous
//
#include <hip/hip_runtime.h>
#include <hip/hip_bf16.h>

#define BB 16
#define NN 512
#define DD 64
#define BN_ROWS (BB * NN)   // 8192
#define WPAD 65             // padded LDS row for W1/W2 (bank-spread)

typedef unsigned short ushort;
typedef unsigned int uint;
typedef short bf16x8 __attribute__((ext_vector_type(8)));   // 8 bf16 = 4 VGPRs
typedef float f32x4  __attribute__((ext_vector_type(4)));   // MFMA acc

// ws layout: stats[128] | wpf fp32 frag-ordered [4096] | xbf bf16 frag-ordered [524288]
// R27 = R25 (exact tanh, fused pass, XCD swizzle) + W1/W2 staged into padded
// LDS via coalesced loads (kills the 8k uncoalesced L1 transactions per block
// in the projection tail — present in all 13 plateau variants).

__device__ __forceinline__ uint pkbf2(float lo, float hi) {
    union { float f; uint u; } a, b; a.f = lo; b.f = hi;
    return __builtin_amdgcn_perm(b.u + 0x8000u, a.u + 0x8000u, 0x07060302u);
}
__device__ __forceinline__ float bflo(uint u) {
    union { uint i; float f; } c; c.i = u << 16; return c.f;
}
__device__ __forceinline__ float bfhi(uint u) {
    union { uint i; float f; } c; c.i = u & 0xffff0000u; return c.f;
}

// no clamp: e=inf -> rcp=0 -> 1 (correct limit); e=0 -> -1 (correct)
__device__ __forceinline__ float fast_tanh(float x) {
    const float e = __builtin_amdgcn_exp2f(x * 2.885390081777927f); // 2x*log2(e)
    return 1.0f - 2.0f * __builtin_amdgcn_rcpf(e + 1.0f);
}

// One-time: x -> bf16 B-frag order; Wp -> fp32 A-frag order; zero stats.
__global__ __launch_bounds__(256) void prep_kernel(
    const float* __restrict__ x, const float* __restrict__ Wp,
    float* __restrict__ wpf, ushort* __restrict__ xbf, float* __restrict__ stats)
{
    const int tid = blockIdx.x * 256 + threadIdx.x;     // grid 256 -> 0..65535
    const int b = tid >> 12, rem = tid & 4095;
    const int jt = rem >> 7, ks = (rem >> 6) & 1, lane = rem & 63;
    const int qd = lane >> 4, ln = lane & 15;
    const float* __restrict__ src =
        x + ((size_t)(b * NN + jt * 16 + ln)) * DD + ks * 32 + qd * 8;
    const float4 v0 = *(const float4*)src;
    const float4 v1 = *(const float4*)(src + 4);
    uint4 o;
    o.x = pkbf2(v0.x, v0.y); o.y = pkbf2(v0.z, v0.w);
    o.z = pkbf2(v1.x, v1.y); o.w = pkbf2(v1.z, v1.w);
    ((uint4*)xbf)[tid] = o;                              // coalesced
    if (tid < DD * DD) {
        const int oo = tid >> 6, d = tid & 63;
        const int mt = oo >> 4, l2 = oo & 15;
        const int k2 = d >> 5, q2 = (d >> 3) & 3, e = d & 7;
        wpf[(((mt * 2 + k2) * 64) + (q2 * 16 + l2)) * 8 + e] = Wp[tid];
    }
    if (tid < 128) stats[tid] = 0.0f;
}

// One block (512 thr, 8 waves) per (b,i); wave wv owns j-tiles wv*4..wv*4+3.
// XCD swizzle: b = (blk&7)*2 + ((blk>>3)&1), i = blk>>4.
__global__ __launch_bounds__(512, 3) void attn_kernel(
    const float* __restrict__ x,  const float* __restrict__ wpf,
    const ushort* __restrict__ xbf,
    const float* __restrict__ bp, const float* __restrict__ aw,
    const float* __restrict__ W1, const float* __restrict__ b1,
    const float* __restrict__ W2, const float* __restrict__ b2,
    float* __restrict__ out, float* __restrict__ stats)
{
    __shared__ float part[8][DD];                   // 2 KB (reused twice)
    __shared__ __align__(16) float s_xi[DD], s_agg[DD], s_bp[DD], s_aw[DD];
    __shared__ float s_esum[8];
    __shared__ float sW1[DD * WPAD], sW2[DD * WPAD];   // 32.5 KB padded

    const int t = threadIdx.x;                      // 0..511
    const int wv = t >> 6, lane = t & 63;
    const int blk = blockIdx.x;                     // 0..8191
    const int b = (blk & 7) * 2 + ((blk >> 3) & 1); // XCD-local b
    const int i = blk >> 4;                         // 0..511
    const int row = b * NN + i;
    const int qd = lane >> 4, ln = lane & 15;
    const ushort* __restrict__ xb16 = xbf + (size_t)b * (NN * DD);

    // coalesced staging of W1/W2 into padded LDS: thread t -> elems t*8..t*8+7
    {
        const int o = t >> 3, d = (t & 7) * 8;      // row o, col d
        const float4 a0 = *(const float4*)(W1 + o * DD + d);
        const float4 a1 = *(const float4*)(W1 + o * DD + d + 4);
        const float4 c0 = *(const float4*)(W2 + o * DD + d);
        const float4 c1 = *(const float4*)(W2 + o * DD + d + 4);
        float* w1r = sW1 + o * WPAD + d;
        float* w2r = sW2 + o * WPAD + d;
        w1r[0]=a0.x; w1r[1]=a0.y; w1r[2]=a0.z; w1r[3]=a0.w;
        w1r[4]=a1.x; w1r[5]=a1.y; w1r[6]=a1.z; w1r[7]=a1.w;
        w2r[0]=c0.x; w2r[1]=c0.y; w2r[2]=c0.z; w2r[3]=c0.w;
        w2r[4]=c1.x; w2r[5]=c1.y; w2r[6]=c1.z; w2r[7]=c1.w;
    }
    if (t < DD) {
        s_bp[t] = bp[t];
        s_aw[t] = aw[t];
        s_xi[t] = x[(size_t)row * DD + t];
    }
    __syncthreads();

    float xiv[2][8];
    #pragma unroll
    for (int ks = 0; ks < 2; ++ks) {
        const float4 a = *(const float4*)(s_xi + ks * 32 + qd * 8);
        const float4 c = *(const float4*)(s_xi + ks * 32 + qd * 8 + 4);
        xiv[ks][0]=a.x; xiv[ks][1]=a.y; xiv[ks][2]=a.z; xiv[ks][3]=a.w;
        xiv[ks][4]=c.x; xiv[ks][5]=c.y; xiv[ks][6]=c.z; xiv[ks][7]=c.w;
    }

    // A-frags: Wp⊙xi in bf16, g = mt*2+ks
    bf16x8 afrag[8];
    #pragma unroll
    for (int g = 0; g < 8; ++g) {
        const int ks = g & 1;
        const float4 wa = *(const float4*)(wpf + (g * 64 + lane) * 8);
        const float4 wb = *(const float4*)(wpf + (g * 64 + lane) * 8 + 4);
        union { bf16x8 v; uint u[4]; } p;
        p.u[0] = pkbf2(wa.x * xiv[ks][0], wa.y * xiv[ks][1]);
        p.u[1] = pkbf2(wa.z * xiv[ks][2], wa.w * xiv[ks][3]);
        p.u[2] = pkbf2(wb.x * xiv[ks][4], wb.y * xiv[ks][5]);
        p.u[3] = pkbf2(wb.z * xiv[ks][6], wb.w * xiv[ks][7]);
        afrag[g] = p.v;
    }

    float bpv[16], awv[16];
    #pragma unroll
    for (int mt = 0; mt < 4; ++mt)
        #pragma unroll
        for (int r = 0; r < 4; ++r) {
            bpv[mt * 4 + r] = s_bp[mt * 16 + qd * 4 + r];
            awv[mt * 4 + r] = s_aw[mt * 16 + qd * 4 + r];
        }

    // ---- FUSED score + aggregate: 4 j-tiles for this wave ----
    float vacc[16];
    #pragma unroll
    for (int k = 0; k < 16; ++k) vacc[k] = 0.0f;
    float esum = 0.0f;

    #pragma unroll
    for (int tt = 0; tt < 4; ++tt) {
        const int tile = wv * 4 + tt;
        union { bf16x8 v; uint4 u; } b0, b1u;
        b0.v  = *(const bf16x8*)(xb16 + ((tile * 2 + 0) * 64 + lane) * 8);
        b1u.v = *(const bf16x8*)(xb16 + ((tile * 2 + 1) * 64 + lane) * 8);

        float s0 = 0.0f, s1 = 0.0f, s2 = 0.0f, s3 = 0.0f;
        #pragma unroll
        for (int mt = 0; mt < 4; ++mt) {
            f32x4 acc = { bpv[mt*4+0], bpv[mt*4+1], bpv[mt*4+2], bpv[mt*4+3] };
            acc = __builtin_amdgcn_mfma_f32_16x16x32_bf16(afrag[mt*2+0], b0.v,  acc, 0, 0, 0);
            acc = __builtin_amdgcn_mfma_f32_16x16x32_bf16(afrag[mt*2+1], b1u.v, acc, 0, 0, 0);
            s0 = fmaf(awv[mt*4+0], fast_tanh(acc[0]), s0);
            s1 = fmaf(awv[mt*4+1], fast_tanh(acc[1]), s1);
            s2 = fmaf(awv[mt*4+2], fast_tanh(acc[2]), s2);
            s3 = fmaf(awv[mt*4+3], fast_tanh(acc[3]), s3);
        }
        float sj = (s0 + s1) + (s2 + s3);
        sj += __shfl_xor(sj, 16);
        sj += __shfl_xor(sj, 32);        // all quads: s for j = tile*16 + ln

        const float e = __builtin_amdgcn_exp2f(sj * 1.4426950408889634f);
        esum += e;
        vacc[0]  = fmaf(e, bflo(b0.u.x),  vacc[0]);
        vacc[1]  = fmaf(e, bfhi(b0.u.x),  vacc[1]);
        vacc[2]  = fmaf(e, bflo(b0.u.y),  vacc[2]);
        vacc[3]  = fmaf(e, bfhi(b0.u.y),  vacc[3]);
        vacc[4]  = fmaf(e, bflo(b0.u.z),  vacc[4]);
        vacc[5]  = fmaf(e, bfhi(b0.u.z),  vacc[5]);
        vacc[6]  = fmaf(e, bflo(b0.u.w),  vacc[6]);
        vacc[7]  = fmaf(e, bfhi(b0.u.w),  vacc[7]);
        vacc[8]  = fmaf(e, bflo(b1u.u.x), vacc[8]);
        vacc[9]  = fmaf(e, bfhi(b1u.u.x), vacc[9]);
        vacc[10] = fmaf(e, bflo(b1u.u.y), vacc[10]);
        vacc[11] = fmaf(e, bfhi(b1u.u.y), vacc[11]);
        vacc[12] = fmaf(e, bflo(b1u.u.z), vacc[12]);
        vacc[13] = fmaf(e, bfhi(b1u.u.z), vacc[13]);
        vacc[14] = fmaf(e, bflo(b1u.u.w), vacc[14]);
        vacc[15] = fmaf(e, bfhi(b1u.u.w), vacc[15]);
    }

    // reduce over ln within wave
    #pragma unroll
    for (int off = 1; off < 16; off <<= 1) {
        esum += __shfl_xor(esum, off);
        #pragma unroll
        for (int k = 0; k < 16; ++k)
            vacc[k] += __shfl_xor(vacc[k], off);
    }
    if (lane == 0) s_esum[wv] = esum;
    if (ln == 0) {
        #pragma unroll
        for (int k = 0; k < 16; ++k)
            part[wv][(k >> 3) * 32 + qd * 8 + (k & 7)] = vacc[k];
    }
    __syncthreads();

    // block combine: agg[d] = (Σ_wv part[wv][d]) / (Σ_wv esum[wv])
    if (t < DD) {
        const float tot = ((s_esum[0] + s_esum[1]) + (s_esum[2] + s_esum[3]))
                        + ((s_esum[4] + s_esum[5]) + (s_esum[6] + s_esum[7]));
        const float inv = 1.0f / tot;
        const float a = ((part[0][t] + part[1][t]) + (part[2][t] + part[3][t]))
                      + ((part[4][t] + part[5][t]) + (part[6][t] + part[7][t]));
        s_agg[t] = a * inv;
    }
    __syncthreads();

    // projection from LDS: thread (o, q) sums 8 d's; 2-way bank alias = free
    {
        const int o = t & 63, q = t >> 6;
        const float* __restrict__ w1 = sW1 + o * WPAD + q * 8;
        const float* __restrict__ w2 = sW2 + o * WPAD + q * 8;
        const float* __restrict__ ag = s_agg + q * 8;
        const float* __restrict__ xi = s_xi + q * 8;
        float v = 0.0f;
        #pragma unroll
        for (int d = 0; d < 8; ++d)
            v = fmaf(w1[d], ag[d], fmaf(w2[d], xi[d], v));
        part[q][o] = v;
    }
    __syncthreads();
    if (t < DD) {
        const int o = t;
        const float v = b1[o] + b2[o]
            + ((part[0][o] + part[1][o]) + (part[2][o] + part[3][o]))
            + ((part[4][o] + part[5][o]) + (part[6][o] + part[7][o]));
        out[(size_t)row * DD + o] = v;     // pre-BN x_out into d_out
        atomicAdd(&stats[o], v);
        atomicAdd(&stats[64 + o], v * v);
    }
}

// BN (batch stats, biased var) + selu, IN PLACE on out; float4 I/O.
__global__ __launch_bounds__(256) void final_kernel(
    const float* __restrict__ stats,
    const float* __restrict__ gamma, const float* __restrict__ beta,
    float* __restrict__ out)
{
    __shared__ float smu[DD], sga[DD], sbe[DD];
    if (threadIdx.x < DD) {
        const int o = threadIdx.x;
        const float mean = stats[o] * (1.0f / BN_ROWS);
        const float var  = stats[64 + o] * (1.0f / BN_ROWS) - mean * mean;
        smu[o] = mean;
        sga[o] = gamma[o] / sqrtf(var + 1e-5f);
        sbe[o] = beta[o];
    }
    __syncthreads();
    const int i4 = blockIdx.x * 256 + threadIdx.x;   // grid 512 -> exactly 131072
    const int o0 = (i4 & 15) * 4;
    const float4 v = ((const float4*)out)[i4];
    float r[4] = { v.x, v.y, v.z, v.w };
    #pragma unroll
    for (int c = 0; c < 4; ++c) {
        const float nrm = (r[c] - smu[o0 + c]) * sga[o0 + c] + sbe[o0 + c];
        r[c] = nrm > 0.0f
            ? 1.0507009873554805f * nrm
            : 1.7580993408473766f * expm1f(nrm);
    }
    ((float4*)out)[i4] = make_float4(r[0], r[1], r[2], r[3]);
}

extern "C" void kernel_launch(void* const* d_in, const int* in_sizes, int n_in,
                              void* d_out, int out_size, void* d_ws, size_t ws_size,
                              hipStream_t stream)
{
    const float* x  = (const float*)d_in[0];
    const float* Wp = (const float*)d_in[1];  // W_att_proj
    const float* bp = (const float*)d_in[2];  // b_att_proj
    const float* aw = (const float*)d_in[3];  // att_weight
    const float* W1 = (const float*)d_in[4];  // W_with
    const float* b1 = (const float*)d_in[5];  // b_with
    const float* W2 = (const float*)d_in[6];  // W_without
    const float* b2 = (const float*)d_in[7];  // b_without
    const float* ga = (const float*)d_in[8];  // gamma
    const float* be = (const float*)d_in[9];  // beta

    float*  stats = (float*)d_ws;                       // 128 floats
    float*  wpf   = stats + 128;                        // 4096 fp32 (A-frag order)
    ushort* xbf   = (ushort*)(wpf + DD * DD);           // 524288 bf16 (B-frag order)
    float*  out   = (float*)d_out;                      // fp32 output

    prep_kernel<<<256, 256, 0, stream>>>(x, Wp, wpf, xbf, stats);
    attn_kernel<<<BN_ROWS, 512, 0, stream>>>(x, wpf, xbf, bp, aw, W1, b1, W2, b2, out, stats);
    final_kernel<<<512, 256, 0, stream>>>(stats, ga, be, out);
}